// Round 6
// baseline (594.352 us; speedup 1.0000x reference)
//
#include <hip/hip_runtime.h>

#define B_SZ 128
#define IN_CAPS 1152
#define N_CAPS 16
#define DIM 16

#define IPT 16                        // i's per pass-block
#define ICN (IN_CAPS / IPT)           // 72 partial slices
#define OUT_ELEMS (B_SZ * N_CAPS * DIM)   // 32768 floats per acc buffer
#define SLICE OUT_ELEMS
#define PR_STRIDE 20                  // LDS row stride (b128-aligned, covers all 32 banks)

// squash of one (b,n,:) row read from global: out = squash(accrow + bb).
__device__ __forceinline__ void squash_row(const float* __restrict__ accrow,
                                           const float bb[16], float out[16])
{
    float s[16], s2 = 0.f;
    #pragma unroll
    for (int q = 0; q < 4; ++q) {
        float4 a = ((const float4*)accrow)[q];
        s[4*q+0] = a.x + bb[4*q+0]; s[4*q+1] = a.y + bb[4*q+1];
        s[4*q+2] = a.z + bb[4*q+2]; s[4*q+3] = a.w + bb[4*q+3];
    }
    #pragma unroll
    for (int e = 0; e < 16; ++e) s2 = fmaf(s[e], s[e], s2);
    float sc = sqrtf(s2) / (1.0f + s2);      // s2/(1+s2)/sqrt(s2)
    #pragma unroll
    for (int e = 0; e < 16; ++e) out[e] = s[e] * sc;
}

// Fused routing pass. R5 lesson: per-thread live state must fit ANY allocation
// the backend picks. 1 b per thread (acc[16] persistent, ~45 transient), pr in
// LDS (not regs), waves_per_eu(4,4) pins the budget to exactly 128 VGPRs
// (forbids both the 64-VGPR occupancy squeeze and >4-wave targets).
// thread = (n = tid&15, bh = tid>>4), b = bt*16+bh. Softmax over n = lanes'
// low 4 bits (shfl_xor 1,2,4,8 stays within an n-group).
// MODE 0: c = 1/16.  MODE 1: pr = squash(accA+B).  MODE 2: pr = sq(accA+B)+sq(accB+B).
template<int MODE>
__global__ __launch_bounds__(256) __attribute__((amdgpu_waves_per_eu(4, 4)))
void caps_pass(const float* __restrict__ x, const float* __restrict__ W,
               const float* __restrict__ Bb,
               const float* __restrict__ accA, const float* __restrict__ accB,
               float* __restrict__ partial)
{
    const int tid = threadIdx.x;
    const int n   = tid & 15;
    const int bh  = tid >> 4;
    const int ic  = blockIdx.x;               // 0..71
    const int i0  = ic * IPT;
    const int b   = blockIdx.y * 16 + bh;

    __shared__ float prs[256 * PR_STRIDE];    // 20 KB; row stride 20 -> conflict-free b128

    if (MODE > 0) {
        float bb[16];
        #pragma unroll
        for (int q = 0; q < 4; ++q) {
            float4 a = ((const float4*)(Bb + (n << 4)))[q];
            bb[4*q+0] = a.x; bb[4*q+1] = a.y; bb[4*q+2] = a.z; bb[4*q+3] = a.w;
        }
        float pr[16];
        squash_row(accA + ((size_t)b << 8) + (n << 4), bb, pr);
        if (MODE == 2) {
            float qq[16];
            squash_row(accB + ((size_t)b << 8) + (n << 4), bb, qq);
            #pragma unroll
            for (int e = 0; e < 16; ++e) pr[e] += qq[e];
        }
        float4* dst = (float4*)&prs[tid * PR_STRIDE];   // tid*80 B: 16B-aligned
        #pragma unroll
        for (int q = 0; q < 4; ++q)
            dst[q] = make_float4(pr[4*q], pr[4*q+1], pr[4*q+2], pr[4*q+3]);
        __syncthreads();
    }

    float acc[16];
    #pragma unroll
    for (int e = 0; e < 16; ++e) acc[e] = 0.f;

    const float* wbase = W + ((size_t)n * IN_CAPS + i0) * 128;   // W[n][i][e][d]

    #pragma unroll 1   // unrolling would inflate live W-load windows past budget
    for (int ii = 0; ii < IPT; ++ii) {
        const int i = i0 + ii;

        const float4* xp = (const float4*)(x + ((size_t)b * IN_CAPS + i) * 8);
        float4 xa = xp[0], xb = xp[1];
        float xr[8] = {xa.x, xa.y, xa.z, xa.w, xb.x, xb.y, xb.z, xb.w};

        float pr[16];
        if (MODE > 0) {
            const float4* pp = (const float4*)&prs[tid * PR_STRIDE];
            #pragma unroll
            for (int q = 0; q < 4; ++q) {
                float4 v = pp[q];
                pr[4*q+0] = v.x; pr[4*q+1] = v.y; pr[4*q+2] = v.z; pr[4*q+3] = v.w;
            }
        }

        const float4* wp = (const float4*)(wbase + (size_t)ii * 128);
        float hat[16];
        float lg = 0.f;
        #pragma unroll
        for (int e = 0; e < 16; ++e) {
            float4 wa = wp[2*e], wb = wp[2*e+1];    // W streamed: 8-float window
            float h = 0.f;
            h = fmaf(xr[0], wa.x, h); h = fmaf(xr[1], wa.y, h);
            h = fmaf(xr[2], wa.z, h); h = fmaf(xr[3], wa.w, h);
            h = fmaf(xr[4], wb.x, h); h = fmaf(xr[5], wb.y, h);
            h = fmaf(xr[6], wb.z, h); h = fmaf(xr[7], wb.w, h);
            hat[e] = h;
            if (MODE > 0) lg = fmaf(pr[e], h, lg);  // logit: in-thread e-dot
        }

        float c;
        if (MODE > 0) {
            float m = lg;
            #pragma unroll
            for (int msk = 8; msk >= 1; msk >>= 1)
                m = fmaxf(m, __shfl_xor(m, msk));
            float p = __expf(lg - m);
            float z = p;
            #pragma unroll
            for (int msk = 8; msk >= 1; msk >>= 1)
                z += __shfl_xor(z, msk);
            c = p / z;
        } else {
            c = 1.0f / 16.0f;                       // softmax of all-zero logits
        }

        #pragma unroll
        for (int e = 0; e < 16; ++e)
            acc[e] = fmaf(c, hat[e], acc[e]);
    }

    // Deterministic partial write: partial[ic][b][n][e], 4 dwordx4 stores.
    float* p0 = partial + ((size_t)ic << 15) + ((size_t)b << 8) + (n << 4);
    #pragma unroll
    for (int q = 0; q < 4; ++q)
        ((float4*)p0)[q] = make_float4(acc[4*q], acc[4*q+1], acc[4*q+2], acc[4*q+3]);
}

// Reduce 72 partial slices -> acc (raw sums); FINAL: add B, squash, write out.
// float4 granularity: pos = b*64 + n*4 + eg (8192 positions). 128 blocks x 256:
// 64 positions/block, 4 groups x 18 slices, LDS combine.
template<bool FINAL>
__global__ __launch_bounds__(256)
void caps_reduce(const float4* __restrict__ partial, const float* __restrict__ Bb,
                 float4* __restrict__ acc, float4* __restrict__ out)
{
    const int tid = threadIdx.x;
    const int ps  = tid & 63;
    const int pos = blockIdx.x * 64 + ps;
    const int grp = tid >> 6;

    float4 s = make_float4(0.f, 0.f, 0.f, 0.f);
    #pragma unroll
    for (int k = 0; k < ICN / 4; ++k) {
        float4 v = partial[(size_t)(grp * (ICN / 4) + k) * (SLICE / 4) + pos];
        s.x += v.x; s.y += v.y; s.z += v.z; s.w += v.w;
    }

    __shared__ float4 red[4][64];
    red[grp][ps] = s;
    __syncthreads();

    if (tid < 64) {
        float4 a = red[0][ps], b = red[1][ps], c = red[2][ps], d = red[3][ps];
        float4 t = make_float4(a.x + b.x + c.x + d.x, a.y + b.y + c.y + d.y,
                               a.z + b.z + c.z + d.z, a.w + b.w + c.w + d.w);
        if (!FINAL) {
            acc[pos] = t;
        } else {
            float4 bb = ((const float4*)Bb)[pos & 63];
            t.x += bb.x; t.y += bb.y; t.z += bb.z; t.w += bb.w;
            // e-row = 4 adjacent lanes (eg = pos&3): combine via shfl_xor(1,2)
            float s2 = t.x*t.x + t.y*t.y + t.z*t.z + t.w*t.w;
            s2 += __shfl_xor(s2, 1);
            s2 += __shfl_xor(s2, 2);
            float sc = sqrtf(s2) / (1.0f + s2);
            t.x *= sc; t.y *= sc; t.z *= sc; t.w *= sc;
            out[pos] = t;
        }
    }
}

extern "C" void kernel_launch(void* const* d_in, const int* in_sizes, int n_in,
                              void* d_out, int out_size, void* d_ws, size_t ws_size,
                              hipStream_t stream)
{
    const float* x  = (const float*)d_in[0];   // [128,1152,8]
    const float* W  = (const float*)d_in[1];   // [16,1152,16,8]
    const float* Bb = (const float*)d_in[2];   // [16,16]
    float4* out = (float4*)d_out;              // [128,16,16]

    float* accA    = (float*)d_ws;             // 128 KB
    float* accB    = accA + OUT_ELEMS;         // 128 KB
    float* partial = accB + OUT_ELEMS;         // 72 x 128 KB = 9.2 MB

    dim3 pg(ICN, B_SZ / 16);   // 72 x 8 = 576 blocks

    caps_pass<0><<<pg, 256, 0, stream>>>(x, W, Bb, nullptr, nullptr, partial);
    caps_reduce<false><<<128, 256, 0, stream>>>((const float4*)partial, Bb, (float4*)accA, nullptr);
    caps_pass<1><<<pg, 256, 0, stream>>>(x, W, Bb, accA, nullptr, partial);
    caps_reduce<false><<<128, 256, 0, stream>>>((const float4*)partial, Bb, (float4*)accB, nullptr);
    caps_pass<2><<<pg, 256, 0, stream>>>(x, W, Bb, accA, accB, partial);
    caps_reduce<true><<<128, 256, 0, stream>>>((const float4*)partial, Bb, nullptr, out);
}

// Round 7
// 168.243 us; speedup vs baseline: 3.5327x; 3.5327x over previous
//
#include <hip/hip_runtime.h>

#define B_SZ 128
#define IN_CAPS 1152
#define N_CAPS 16
#define DIM 16

#define IPT 8                         // i's per pass-block
#define ICN (IN_CAPS / IPT)           // 144 partial slices
#define OUT_ELEMS (B_SZ * N_CAPS * DIM)   // 32768
#define PAIR_STRIDE 140               // LDS floats per (isub,n) W row-block (128 + 12 pad, 16B-aligned)

// fp32 -> bf16 round-to-nearest-even
__device__ __forceinline__ unsigned short f2bf(float f) {
    unsigned u = __float_as_uint(f);
    u = u + 0x7fffu + ((u >> 16) & 1u);
    return (unsigned short)(u >> 16);
}
__device__ __forceinline__ float bf2f(unsigned short h) {
    return __uint_as_float(((unsigned)h) << 16);
}

// Fused routing pass.
// R5/R6 lessons: (a) W global loads were lane-divergent (16 lines/instr, L1
// sequencing-bound) -> stage W through LDS with coalesced loads; (b) per-thread
// live state must be ~<=96 -> split e across lanes: lane = eg(2b)*16 + n(4b),
// wave w owns b = bt*16 + w*4 + {0..3}. Per-thread: Wreg[4][8] (one i, 4 e-rows,
// pinned), pr[4][4], acc[4][4]. No atomics; partial written bf16 (error ~1e-3
// vs 1.57e-2 threshold), deterministic slice per (ic) block.
// MODE 0: c = 1/16.  MODE 1: pr = squash(accA+B).  MODE 2: pr = sq(accA+B)+sq(accB+B).
template<int MODE>
__global__ __launch_bounds__(256)
void caps_pass(const float* __restrict__ x, const float* __restrict__ W,
               const float* __restrict__ Bb,
               const float* __restrict__ accA, const float* __restrict__ accB,
               unsigned short* __restrict__ partial)
{
    const int tid = threadIdx.x;
    const int n   = tid & 15;
    const int eg  = (tid >> 4) & 3;           // e = eg*4 + r
    const int w   = tid >> 6;                 // wave id
    const int ic  = blockIdx.x;               // 0..143
    const int bt  = blockIdx.y;               // 0..7
    const int bb0 = bt * 16 + w * 4;          // wave's 4 b's: bb0..bb0+3

    __shared__ float lw[32 * PAIR_STRIDE];    // 2 i's x 16 n staged W (17.9 KB)

    // B row slice for (n, eg): same for all b
    float4 bb4 = ((const float4*)(Bb + (n << 4)))[eg];

    // pr[bq][4]: prev-output slice for (b, n, eg*4..+3), squashed in-register.
    // squash needs full-e sum: own 4 e's + shfl over eg lanes (bits 4,5).
    float pr[4][4];
    if (MODE > 0) {
        #pragma unroll
        for (int bq = 0; bq < 4; ++bq) {
            const int b = bb0 + bq;
            float4 a = *(const float4*)(accA + ((size_t)b << 8) + (n << 4) + (eg << 2));
            float s0 = a.x + bb4.x, s1 = a.y + bb4.y, s2v = a.z + bb4.z, s3 = a.w + bb4.w;
            float q2 = s0*s0 + s1*s1 + s2v*s2v + s3*s3;
            q2 += __shfl_xor(q2, 16);
            q2 += __shfl_xor(q2, 32);
            float sc = sqrtf(q2) / (1.0f + q2);
            pr[bq][0] = s0*sc; pr[bq][1] = s1*sc; pr[bq][2] = s2v*sc; pr[bq][3] = s3*sc;
            if (MODE == 2) {
                float4 a2 = *(const float4*)(accB + ((size_t)b << 8) + (n << 4) + (eg << 2));
                float t0 = a2.x + bb4.x, t1 = a2.y + bb4.y, t2 = a2.z + bb4.z, t3 = a2.w + bb4.w;
                float r2 = t0*t0 + t1*t1 + t2*t2 + t3*t3;
                r2 += __shfl_xor(r2, 16);
                r2 += __shfl_xor(r2, 32);
                float sc2 = sqrtf(r2) / (1.0f + r2);
                pr[bq][0] += t0*sc2; pr[bq][1] += t1*sc2; pr[bq][2] += t2*sc2; pr[bq][3] += t3*sc2;
            }
        }
        #pragma unroll
        for (int bq = 0; bq < 4; ++bq)
            #pragma unroll
            for (int r = 0; r < 4; ++r)
                asm volatile("" : "+v"(pr[bq][r]));   // pin: no remat
    }

    float acc[4][4];
    #pragma unroll
    for (int bq = 0; bq < 4; ++bq)
        #pragma unroll
        for (int r = 0; r < 4; ++r) acc[bq][r] = 0.f;

    const int i_base = ic * IPT;

    for (int ig = 0; ig < IPT / 2; ++ig) {
        const int i0 = i_base + ig * 2;
        __syncthreads();                       // protect LDS before overwrite
        {   // stage 2 i's x 16 n, coalesced: thread t -> pair p = t>>3, chunk k = t&7
            const int p = tid >> 3, k = tid & 7;
            const int nn = p & 15, isub = p >> 4;
            const float4* src = (const float4*)(W + ((size_t)(nn * IN_CAPS + i0 + isub)) * 128);
            #pragma unroll
            for (int j = 0; j < 4; ++j) {
                float4 v = src[k + 8 * j];
                *(float4*)&lw[p * PAIR_STRIDE + (k + 8 * j) * 4] = v;
            }
        }
        __syncthreads();

        #pragma unroll
        for (int isub = 0; isub < 2; ++isub) {
            const int i = i0 + isub;
            // Wreg: this thread's 4 e-rows of W[n][i] from LDS (reused over 4 b's)
            float Wreg[4][8];
            const float* wrow = &lw[(isub * 16 + n) * PAIR_STRIDE + (eg << 5)];
            #pragma unroll
            for (int r = 0; r < 4; ++r) {
                float4 a = *(const float4*)&wrow[r * 8];
                float4 b4 = *(const float4*)&wrow[r * 8 + 4];
                Wreg[r][0] = a.x;  Wreg[r][1] = a.y;  Wreg[r][2] = a.z;  Wreg[r][3] = a.w;
                Wreg[r][4] = b4.x; Wreg[r][5] = b4.y; Wreg[r][6] = b4.z; Wreg[r][7] = b4.w;
            }
            #pragma unroll
            for (int r = 0; r < 4; ++r)
                #pragma unroll
                for (int d = 0; d < 8; ++d)
                    asm volatile("" : "+v"(Wreg[r][d]));   // pin: no remat via LDS

            #pragma unroll
            for (int bq = 0; bq < 4; ++bq) {
                const int b = bb0 + bq;
                // x[b][i][0:8]: wave-uniform 32B -> L1 broadcast
                const float4* xp = (const float4*)(x + ((size_t)b * IN_CAPS + i) * 8);
                float4 xa = xp[0], xb = xp[1];
                float xr[8] = {xa.x, xa.y, xa.z, xa.w, xb.x, xb.y, xb.z, xb.w};

                float hat[4];
                #pragma unroll
                for (int r = 0; r < 4; ++r) {
                    float h = 0.f;
                    #pragma unroll
                    for (int d = 0; d < 8; ++d) h = fmaf(xr[d], Wreg[r][d], h);
                    hat[r] = h;
                }

                float c;
                if (MODE > 0) {
                    float lg = pr[bq][0]*hat[0] + pr[bq][1]*hat[1]
                             + pr[bq][2]*hat[2] + pr[bq][3]*hat[3];
                    lg += __shfl_xor(lg, 16);          // sum over eg
                    lg += __shfl_xor(lg, 32);
                    // softmax over n (lanes' low 4 bits). No max-sub: |lg| <~ 13, exp-safe.
                    float p = __expf(lg);
                    float z = p;
                    z += __shfl_xor(z, 1);
                    z += __shfl_xor(z, 2);
                    z += __shfl_xor(z, 4);
                    z += __shfl_xor(z, 8);
                    c = p / z;
                } else {
                    c = 1.0f / 16.0f;                  // softmax of all-zero logits
                }

                #pragma unroll
                for (int r = 0; r < 4; ++r)
                    acc[bq][r] = fmaf(c, hat[r], acc[bq][r]);
            }
        }
    }

    // Epilogue: bf16 partial[ic][b][n][e], one uint2 (4 bf16) per (bq): coalesced.
    #pragma unroll
    for (int bq = 0; bq < 4; ++bq) {
        const int b = bb0 + bq;
        unsigned short* pp = partial + (((size_t)ic * B_SZ + b) << 8) + (n << 4) + (eg << 2);
        uint2 pk;
        pk.x = ((unsigned)f2bf(acc[bq][1]) << 16) | f2bf(acc[bq][0]);
        pk.y = ((unsigned)f2bf(acc[bq][3]) << 16) | f2bf(acc[bq][2]);
        *(uint2*)pp = pk;
    }
}

// Sum 144 bf16 slices. !FINAL: acc[g] = sum (fp32). FINAL: +B, squash, out.
// One thread per element; e = lanes' low 4 bits -> shfl_xor(1,2,4,8) row-reduce.
template<bool FINAL>
__global__ __launch_bounds__(256)
void caps_reduce(const unsigned short* __restrict__ partial, const float* __restrict__ Bb,
                 float* __restrict__ acc, float* __restrict__ out)
{
    const int g = blockIdx.x * 256 + threadIdx.x;   // g = b*256 + n*16 + e
    float t = 0.f;
    #pragma unroll 8
    for (int s = 0; s < ICN; ++s)
        t += bf2f(partial[(size_t)s * OUT_ELEMS + g]);

    if (!FINAL) {
        acc[g] = t;
    } else {
        t += Bb[g & 255];
        float s2 = t * t;
        s2 += __shfl_xor(s2, 1);
        s2 += __shfl_xor(s2, 2);
        s2 += __shfl_xor(s2, 4);
        s2 += __shfl_xor(s2, 8);
        out[g] = t * (sqrtf(s2) / (1.0f + s2));
    }
}

extern "C" void kernel_launch(void* const* d_in, const int* in_sizes, int n_in,
                              void* d_out, int out_size, void* d_ws, size_t ws_size,
                              hipStream_t stream)
{
    const float* x  = (const float*)d_in[0];   // [128,1152,8]
    const float* W  = (const float*)d_in[1];   // [16,1152,16,8]
    const float* Bb = (const float*)d_in[2];   // [16,16]
    float* out = (float*)d_out;                // [128,16,16] fp32

    float* accA = (float*)d_ws;                         // 128 KB
    float* accB = accA + OUT_ELEMS;                     // 128 KB
    unsigned short* partial = (unsigned short*)(accB + OUT_ELEMS);  // 144 x 64 KB bf16

    dim3 pg(ICN, B_SZ / 16);   // 144 x 8 = 1152 blocks

    caps_pass<0><<<pg, 256, 0, stream>>>(x, W, Bb, nullptr, nullptr, partial);
    caps_reduce<false><<<OUT_ELEMS / 256, 256, 0, stream>>>(partial, Bb, accA, nullptr);
    caps_pass<1><<<pg, 256, 0, stream>>>(x, W, Bb, accA, nullptr, partial);
    caps_reduce<false><<<OUT_ELEMS / 256, 256, 0, stream>>>(partial, Bb, accB, nullptr);
    caps_pass<2><<<pg, 256, 0, stream>>>(x, W, Bb, accA, accB, partial);
    caps_reduce<true><<<OUT_ELEMS / 256, 256, 0, stream>>>(partial, Bb, nullptr, out);
}

// Round 8
// 167.293 us; speedup vs baseline: 3.5528x; 1.0057x over previous
//
#include <hip/hip_runtime.h>

#define B_SZ 128
#define IN_CAPS 1152
#define N_CAPS 16
#define DIM 16

#define IPB 8                         // i's per pass-block
#define ICN (IN_CAPS / IPB)           // 144 partial slices
#define OUT_ELEMS (B_SZ * N_CAPS * DIM)   // 32768

// LDS hat tile: HAT[i_slot(2)][n][b][e] fp32, padded strides for bank spread
#define BSTR 20                       // b-stride (floats): 16 e + 4 pad, 16B-aligned
#define NSTR 324                      // n-stride: 16*20 + 4
#define ISTR (N_CAPS * NSTR)          // 5184 floats per i-slot (20.7 KB)

typedef __attribute__((ext_vector_type(8))) short bf16x8;   // MFMA A/B frag (4 VGPRs)
typedef __attribute__((ext_vector_type(4))) float f32x4;    // MFMA C/D frag

__device__ __forceinline__ unsigned short f2bf(float f) {
    unsigned u = __float_as_uint(f);
    u = u + 0x7fffu + ((u >> 16) & 1u);
    return (unsigned short)(u >> 16);
}
__device__ __forceinline__ float bf2f(unsigned short h) {
    return __uint_as_float(((unsigned)h) << 16);
}
__device__ __forceinline__ unsigned pk2(float lo, float hi) {
    return ((unsigned)f2bf(hi) << 16) | f2bf(lo);
}

// ---- prep: W fp32 -> WB bf16 (same [n][i][e][d] order). 8 el/thread. ----
__global__ __launch_bounds__(256)
void conv_w(const float* __restrict__ W, unsigned short* __restrict__ WB)
{
    size_t g = (size_t)blockIdx.x * 256 + threadIdx.x;
    const float4* src = (const float4*)(W + g * 8);
    float4 a = src[0], b = src[1];
    uint4 o;
    o.x = pk2(a.x, a.y); o.y = pk2(a.z, a.w);
    o.z = pk2(b.x, b.y); o.w = pk2(b.z, b.w);
    *(uint4*)(WB + g * 8) = o;
}

// ---- prep: x[b][i][d] fp32 -> XT[i][b][d] bf16 (transpose for coalesced A-frag loads) ----
__global__ __launch_bounds__(256)
void conv_x(const float* __restrict__ x, unsigned short* __restrict__ XT)
{
    const int tid = threadIdx.x;
    const int i = blockIdx.x * 2 + (tid >> 7);
    const int b = tid & 127;
    const float4* src = (const float4*)(x + ((size_t)b * IN_CAPS + i) * 8);
    float4 a = src[0], c = src[1];
    uint4 o;
    o.x = pk2(a.x, a.y); o.y = pk2(a.z, a.w);
    o.z = pk2(c.x, c.y); o.w = pk2(c.z, c.w);
    *(uint4*)(XT + ((size_t)i * B_SZ + b) * 8) = o;
}

// ---- fused routing pass: MFMA produces hat -> LDS; VALU routing consumes ----
// R7 lesson: 3 identical pass durations incl. no-softmax MODE 0 => the VALU hat
// recompute is the floor. Move it to the matrix pipe (147K MFMAs ~ 0.3us/pass).
// Producer: per (n,i) one mfma_f32_16x16x32_bf16; A = x rows (k>=8 zeroed via
// cndmask, so B's k>=8 junk multiplies zero); D (col=lane&15=e, row=q*4+r=b,
// m89 layout) -> 4 ds_write_b32 into HAT[is][n][b][e] (<=2-way banks).
// Consumer: R7 mapping (n=tid&15, eg, wave w -> b = bt*16+w*4+bq); hat via one
// ds_read_b128; logit in-thread + eg shfl; softmax over n in-lane; acc in regs.
// MODE 0: c=1/16.  MODE 1: pr = squash(accA+B).  MODE 2: pr = sq(accA+B)+sq(accB+B).
template<int MODE>
__global__ __launch_bounds__(256)
void caps_pass(const unsigned short* __restrict__ XT, const unsigned short* __restrict__ WB,
               const float* __restrict__ Bb,
               const float* __restrict__ accA, const float* __restrict__ accB,
               unsigned short* __restrict__ partial)
{
    const int tid  = threadIdx.x;
    const int lane = tid & 63;
    const int w    = tid >> 6;            // wave id
    const int n_c  = tid & 15;            // consumer: n
    const int eg   = (tid >> 4) & 3;      // consumer: e-group (e = eg*4+r)
    const int q    = lane >> 4;           // producer: k-quad / D row-group
    const int em   = lane & 15;           // producer: A m (=b_loc), B col (=e), D col
    const int ic   = blockIdx.x;          // 0..143
    const int bt   = blockIdx.y;          // 0..7
    const int i0   = ic * IPB;
    const int b0   = bt * 16;

    __shared__ float hat_lds[2 * ISTR];   // 41.5 KB -> 3 blocks/CU

    // consumer prologue: pr[bq][r] = routing weights for b = b0 + w*4 + bq
    float pr[4][4];
    if (MODE > 0) {
        const float4 bb4 = ((const float4*)(Bb + (n_c << 4)))[eg];
        #pragma unroll
        for (int bq = 0; bq < 4; ++bq) {
            const int b = b0 + w * 4 + bq;
            float4 a = *(const float4*)(accA + ((size_t)b << 8) + (n_c << 4) + (eg << 2));
            float s0 = a.x + bb4.x, s1 = a.y + bb4.y, s2 = a.z + bb4.z, s3 = a.w + bb4.w;
            float q2 = s0*s0 + s1*s1 + s2*s2 + s3*s3;
            q2 += __shfl_xor(q2, 16);
            q2 += __shfl_xor(q2, 32);
            float sc = sqrtf(q2) / (1.0f + q2);
            pr[bq][0] = s0*sc; pr[bq][1] = s1*sc; pr[bq][2] = s2*sc; pr[bq][3] = s3*sc;
            if (MODE == 2) {
                float4 a2 = *(const float4*)(accB + ((size_t)b << 8) + (n_c << 4) + (eg << 2));
                float t0 = a2.x + bb4.x, t1 = a2.y + bb4.y, t2 = a2.z + bb4.z, t3 = a2.w + bb4.w;
                float r2 = t0*t0 + t1*t1 + t2*t2 + t3*t3;
                r2 += __shfl_xor(r2, 16);
                r2 += __shfl_xor(r2, 32);
                float sc2 = sqrtf(r2) / (1.0f + r2);
                pr[bq][0] += t0*sc2; pr[bq][1] += t1*sc2; pr[bq][2] += t2*sc2; pr[bq][3] += t3*sc2;
            }
        }
        #pragma unroll
        for (int bq = 0; bq < 4; ++bq)
            #pragma unroll
            for (int r = 0; r < 4; ++r)
                asm volatile("" : "+v"(pr[bq][r]));   // pin: no remat
    }

    float acc[4][4];
    #pragma unroll
    for (int bq = 0; bq < 4; ++bq)
        #pragma unroll
        for (int r = 0; r < 4; ++r) acc[bq][r] = 0.f;

    const bf16x8 zfrag = {0,0,0,0,0,0,0,0};

    for (int ch = 0; ch < IPB / 2; ++ch) {
        // ---- produce 2 i's of hat via MFMA ----
        #pragma unroll
        for (int is = 0; is < 2; ++is) {
            const int i = i0 + ch * 2 + is;
            // A-frag: lane (q, m=em) -> x[b0+em][i][0:8] in k 0..7; k>=8 zeroed
            bf16x8 av = *(const bf16x8*)(XT + ((size_t)i * B_SZ + b0 + em) * 8);
            av = (q == 0) ? av : zfrag;
            #pragma unroll
            for (int np = 0; np < 4; ++np) {
                const int n_p = w * 4 + np;
                // B-frag: lane col=em=e -> W[n_p][i][e][0:8] (k>=8 junk * A-zeros)
                bf16x8 bv = *(const bf16x8*)(WB + (((size_t)n_p * IN_CAPS + i) * DIM + em) * 8);
                f32x4 cz = {0.f, 0.f, 0.f, 0.f};
                f32x4 d = __builtin_amdgcn_mfma_f32_16x16x32_bf16(av, bv, cz, 0, 0, 0);
                // D: lane (q, em=e) holds b = q*4 + r
                float* dst = &hat_lds[is * ISTR + n_p * NSTR + (q * 4) * BSTR + em];
                dst[0]        = d[0];
                dst[BSTR]     = d[1];
                dst[2 * BSTR] = d[2];
                dst[3 * BSTR] = d[3];
            }
        }
        __syncthreads();

        // ---- consume: routing over 2 i's x 4 b's ----
        #pragma unroll
        for (int is = 0; is < 2; ++is) {
            #pragma unroll
            for (int bq = 0; bq < 4; ++bq) {
                float4 hv = *(float4*)&hat_lds[is * ISTR + n_c * NSTR + (w * 4 + bq) * BSTR + (eg << 2)];
                float c;
                if (MODE > 0) {
                    float lg = pr[bq][0]*hv.x + pr[bq][1]*hv.y + pr[bq][2]*hv.z + pr[bq][3]*hv.w;
                    lg += __shfl_xor(lg, 16);       // sum over eg
                    lg += __shfl_xor(lg, 32);
                    // softmax over n (lane low 4 bits). |lg| <~ 1.2 -> no max-sub needed.
                    float p = __expf(lg);
                    float z = p;
                    z += __shfl_xor(z, 1);
                    z += __shfl_xor(z, 2);
                    z += __shfl_xor(z, 4);
                    z += __shfl_xor(z, 8);
                    c = p / z;
                } else {
                    c = 1.0f / 16.0f;               // softmax of all-zero logits
                }
                acc[bq][0] = fmaf(c, hv.x, acc[bq][0]);
                acc[bq][1] = fmaf(c, hv.y, acc[bq][1]);
                acc[bq][2] = fmaf(c, hv.z, acc[bq][2]);
                acc[bq][3] = fmaf(c, hv.w, acc[bq][3]);
            }
        }
        __syncthreads();   // before next chunk overwrites LDS
    }

    // epilogue: bf16 partial[ic][b][n][e], uint2 (4 bf16) per bq, coalesced
    #pragma unroll
    for (int bq = 0; bq < 4; ++bq) {
        const int b = b0 + w * 4 + bq;
        unsigned short* pp = partial + (((size_t)ic * B_SZ + b) << 8) + (n_c << 4) + (eg << 2);
        uint2 pk;
        pk.x = pk2(acc[bq][0], acc[bq][1]);
        pk.y = pk2(acc[bq][2], acc[bq][3]);
        *(uint2*)pp = pk;
    }
}

// ---- sum 144 bf16 slices. !FINAL: acc[g] fp32. FINAL: +B, squash, write out. ----
template<bool FINAL>
__global__ __launch_bounds__(256)
void caps_reduce(const unsigned short* __restrict__ partial, const float* __restrict__ Bb,
                 float* __restrict__ acc, float* __restrict__ out)
{
    const int g = blockIdx.x * 256 + threadIdx.x;   // g = b*256 + n*16 + e
    float t = 0.f;
    #pragma unroll 8
    for (int s = 0; s < ICN; ++s)
        t += bf2f(partial[(size_t)s * OUT_ELEMS + g]);

    if (!FINAL) {
        acc[g] = t;
    } else {
        t += Bb[g & 255];
        float s2 = t * t;
        s2 += __shfl_xor(s2, 1);
        s2 += __shfl_xor(s2, 2);
        s2 += __shfl_xor(s2, 4);
        s2 += __shfl_xor(s2, 8);
        out[g] = t * (sqrtf(s2) / (1.0f + s2));
    }
}

extern "C" void kernel_launch(void* const* d_in, const int* in_sizes, int n_in,
                              void* d_out, int out_size, void* d_ws, size_t ws_size,
                              hipStream_t stream)
{
    const float* x  = (const float*)d_in[0];   // [128,1152,8]
    const float* W  = (const float*)d_in[1];   // [16,1152,16,8]
    const float* Bb = (const float*)d_in[2];   // [16,16]
    float* out = (float*)d_out;                // [128,16,16] fp32

    float* accA = (float*)d_ws;                              // 128 KB
    float* accB = accA + OUT_ELEMS;                          // 128 KB
    unsigned short* XT = (unsigned short*)(accB + OUT_ELEMS);      // 2.36 MB bf16
    unsigned short* WB = XT + (size_t)B_SZ * IN_CAPS * 8;          // 4.72 MB bf16
    unsigned short* partial = WB + (size_t)N_CAPS * IN_CAPS * DIM * 8;  // 9.4 MB bf16

    conv_x<<<IN_CAPS / 2, 256, 0, stream>>>(x, XT);
    conv_w<<<(N_CAPS * IN_CAPS * DIM * 8) / (8 * 256), 256, 0, stream>>>(W, WB);

    dim3 pg(ICN, B_SZ / 16);   // 144 x 8 = 1152 blocks

    caps_pass<0><<<pg, 256, 0, stream>>>(XT, WB, Bb, nullptr, nullptr, partial);
    caps_reduce<false><<<OUT_ELEMS / 256, 256, 0, stream>>>(partial, Bb, accA, nullptr);
    caps_pass<1><<<pg, 256, 0, stream>>>(XT, WB, Bb, accA, nullptr, partial);
    caps_reduce<false><<<OUT_ELEMS / 256, 256, 0, stream>>>(partial, Bb, accB, nullptr);
    caps_pass<2><<<pg, 256, 0, stream>>>(XT, WB, Bb, accA, accB, partial);
    caps_reduce<true><<<OUT_ELEMS / 256, 256, 0, stream>>>(partial, Bb, nullptr, out);
}

// Round 9
// 147.184 us; speedup vs baseline: 4.0381x; 1.1366x over previous
//
#include <hip/hip_runtime.h>

#define B_SZ 128
#define IN_CAPS 1152
#define N_CAPS 16
#define DIM 16

#define IPB 16                        // i's per pass-block
#define ICN (IN_CAPS / IPB)           // 72 partial slices
#define OUT_ELEMS (B_SZ * N_CAPS * DIM)   // 32768
// LDS hat tile strides (floats): [ii(2)][b(16)][n(16)][e(16)]
#define NSTR 20                       // 16 e + 4 pad
#define BSTR 324                      // 16*20 + 4
#define ISTR 5184                     // 16*324  (20.7 KB per i-slot)

typedef __attribute__((ext_vector_type(8))) short bf16x8;   // MFMA A/B frag
typedef __attribute__((ext_vector_type(4))) float f32x4;    // MFMA C/D frag

__device__ __forceinline__ unsigned short f2bf(float f) {   // RNE (trunc would bias the 1152-i sum)
    unsigned u = __float_as_uint(f);
    u = u + 0x7fffu + ((u >> 16) & 1u);
    return (unsigned short)(u >> 16);
}
__device__ __forceinline__ float bf2f(unsigned short h) {
    return __uint_as_float(((unsigned)h) << 16);
}
__device__ __forceinline__ unsigned pk2(float lo, float hi) {
    return ((unsigned)f2bf(hi) << 16) | f2bf(lo);
}

// DPP sum over each 16-lane row (VALU pipe — replaces ds_swizzle shuffles).
__device__ __forceinline__ float dpp_sum16(float v) {
    v += __int_as_float(__builtin_amdgcn_update_dpp(0, __float_as_int(v), 0xB1, 0xF, 0xF, true));  // xor1
    v += __int_as_float(__builtin_amdgcn_update_dpp(0, __float_as_int(v), 0x4E, 0xF, 0xF, true));  // xor2
    v += __int_as_float(__builtin_amdgcn_update_dpp(0, __float_as_int(v), 0x124, 0xF, 0xF, true)); // ror4
    v += __int_as_float(__builtin_amdgcn_update_dpp(0, __float_as_int(v), 0x128, 0xF, 0xF, true)); // ror8
    return v;
}
// DPP sum over each 8-lane half-row (for the final-reduce squash).
__device__ __forceinline__ float dpp_sum8(float v) {
    v += __int_as_float(__builtin_amdgcn_update_dpp(0, __float_as_int(v), 0xB1, 0xF, 0xF, true));  // xor1
    v += __int_as_float(__builtin_amdgcn_update_dpp(0, __float_as_int(v), 0x4E, 0xF, 0xF, true));  // xor2
    v += __int_as_float(__builtin_amdgcn_update_dpp(0, __float_as_int(v), 0x141, 0xF, 0xF, true)); // half_mirror (xor4)
    return v;
}

// ---- prep (fused): blocks [0,1152): W fp32 -> WB bf16; [1152,1728): x -> XT[i][b][d] bf16 ----
__global__ __launch_bounds__(256)
void conv_xw(const float* __restrict__ W, const float* __restrict__ x,
             unsigned short* __restrict__ WB, unsigned short* __restrict__ XT)
{
    const int tid = threadIdx.x;
    if (blockIdx.x < 1152) {
        size_t g = (size_t)blockIdx.x * 256 + tid;
        const float4* src = (const float4*)(W + g * 8);
        float4 a = src[0], b = src[1];
        uint4 o = {pk2(a.x, a.y), pk2(a.z, a.w), pk2(b.x, b.y), pk2(b.z, b.w)};
        *(uint4*)(WB + g * 8) = o;
    } else {
        const int bx = blockIdx.x - 1152;          // 0..575
        const int i = bx * 2 + (tid >> 7);
        const int b = tid & 127;
        const float4* src = (const float4*)(x + ((size_t)b * IN_CAPS + i) * 8);
        float4 a = src[0], c = src[1];
        uint4 o = {pk2(a.x, a.y), pk2(a.z, a.w), pk2(c.x, c.y), pk2(c.z, c.w)};
        *(uint4*)(XT + ((size_t)i * B_SZ + b) * 8) = o;
    }
}

// ---- fused routing pass ----
// R8 lesson: ds_swizzle softmax + hat LDS round-trip saturated the per-CU DS
// pipe. Now: e fully in-thread in the consumer (one 64B row read, logit dot &
// squash shuffle-free), softmax-over-n via DPP (VALU pipe), hat fp32 in LDS.
// Producer (R8-proven MFMA): wave w covers n in {4w..4w+3}; per (n,i) one
// mfma 16x16x32 (A = x b-tile, k>=8 zeroed; D col=e, row=q*4+r=b_loc) -> 4
// ds_write_b32 into hat[ii][b][n][e] (2-way banks max).
// Consumer: lane = bq*16 + n?? -> n = lane&15, bq = lane>>4; b_loc = 4w+bq.
// MODE 0: c=1/16.  MODE 1: pr = squash(accA+B).  MODE 2: pr = sq(accA+B)+sq(accB+B).
template<int MODE>
__global__ __launch_bounds__(256)
void caps_pass(const unsigned short* __restrict__ XT, const unsigned short* __restrict__ WB,
               const float* __restrict__ Bb,
               const float* __restrict__ accA, const float* __restrict__ accB,
               unsigned short* __restrict__ partial)
{
    const int tid  = threadIdx.x;
    const int lane = tid & 63;
    const int w    = tid >> 6;
    const int em   = lane & 15;       // producer: A m (=b_loc), B col (=e); consumer: n
    const int q    = lane >> 4;       // producer: k-quad / D row-group; consumer: bq
    const int bt   = blockIdx.x;      // 0..7  (x-major: consecutive blocks share W slice in L2)
    const int ic   = blockIdx.y;      // 0..71
    const int i0   = ic * IPB;
    const int n    = em;
    const int b_loc = 4 * w + q;
    const int b_glb = bt * 16 + b_loc;

    __shared__ float hat_l[2 * ISTR];   // 41.5 KB -> 3 blocks/CU

    // ---- prologue: pr[e] = routing weights for this thread's (b_glb, n), e in-thread ----
    float pr[16];
    if (MODE > 0) {
        const float4* bbp = (const float4*)(Bb + (n << 4));
        const float4* ap  = (const float4*)(accA + ((size_t)b_glb << 8) + (n << 4));
        float s[16], s2 = 0.f;
        #pragma unroll
        for (int k4 = 0; k4 < 4; ++k4) {
            float4 a = ap[k4], bb = bbp[k4];
            s[4*k4+0] = a.x + bb.x; s[4*k4+1] = a.y + bb.y;
            s[4*k4+2] = a.z + bb.z; s[4*k4+3] = a.w + bb.w;
        }
        #pragma unroll
        for (int e = 0; e < 16; ++e) s2 = fmaf(s[e], s[e], s2);
        float sc = sqrtf(s2) / (1.0f + s2);
        #pragma unroll
        for (int e = 0; e < 16; ++e) pr[e] = s[e] * sc;
        if (MODE == 2) {
            const float4* ap2 = (const float4*)(accB + ((size_t)b_glb << 8) + (n << 4));
            float t[16], t2 = 0.f;
            #pragma unroll
            for (int k4 = 0; k4 < 4; ++k4) {
                float4 a = ap2[k4], bb = bbp[k4];
                t[4*k4+0] = a.x + bb.x; t[4*k4+1] = a.y + bb.y;
                t[4*k4+2] = a.z + bb.z; t[4*k4+3] = a.w + bb.w;
            }
            #pragma unroll
            for (int e = 0; e < 16; ++e) t2 = fmaf(t[e], t[e], t2);
            float sc2 = sqrtf(t2) / (1.0f + t2);
            #pragma unroll
            for (int e = 0; e < 16; ++e) pr[e] = fmaf(t[e], sc2, pr[e]);
        }
        #pragma unroll
        for (int e = 0; e < 16; ++e)
            asm volatile("" : "+v"(pr[e]));   // pin: no remat through the chunk loop
    }

    float acc[16];
    #pragma unroll
    for (int e = 0; e < 16; ++e) acc[e] = 0.f;

    #pragma unroll 1
    for (int ch = 0; ch < IPB / 2; ++ch) {
        __syncthreads();                       // previous consume done before overwrite
        // ---- produce 2 i's of hat via MFMA ----
        #pragma unroll
        for (int ii = 0; ii < 2; ++ii) {
            const int i = i0 + ch * 2 + ii;
            uint4 au = {0u, 0u, 0u, 0u};
            if (q == 0)                        // k>=8 rows of A are zero
                au = *(const uint4*)(XT + ((size_t)i * B_SZ + bt * 16 + em) * 8);
            union { uint4 u; bf16x8 v; } ua; ua.u = au;
            #pragma unroll
            for (int np = 0; np < 4; ++np) {
                const int nn = 4 * w + np;
                bf16x8 bv = *(const bf16x8*)(WB + (((size_t)nn * IN_CAPS + i) * DIM + em) * 8);
                f32x4 cz = {0.f, 0.f, 0.f, 0.f};
                f32x4 d = __builtin_amdgcn_mfma_f32_16x16x32_bf16(ua.v, bv, cz, 0, 0, 0);
                // D: lane (q, em=e) holds b_loc = q*4 + r
                float* dst = &hat_l[ii * ISTR + (4 * q) * BSTR + nn * NSTR + em];
                dst[0]        = d[0];
                dst[BSTR]     = d[1];
                dst[2 * BSTR] = d[2];
                dst[3 * BSTR] = d[3];
            }
        }
        __syncthreads();
        // ---- consume: routing, e fully in-thread ----
        #pragma unroll
        for (int ii = 0; ii < 2; ++ii) {
            const float* row = &hat_l[ii * ISTR + b_loc * BSTR + n * NSTR];
            float4 h0 = *(const float4*)(row);
            float4 h1 = *(const float4*)(row + 4);
            float4 h2 = *(const float4*)(row + 8);
            float4 h3 = *(const float4*)(row + 12);
            float c;
            if (MODE > 0) {
                float lg = pr[0]*h0.x + pr[1]*h0.y + pr[2]*h0.z + pr[3]*h0.w
                         + pr[4]*h1.x + pr[5]*h1.y + pr[6]*h1.z + pr[7]*h1.w
                         + pr[8]*h2.x + pr[9]*h2.y + pr[10]*h2.z + pr[11]*h2.w
                         + pr[12]*h3.x + pr[13]*h3.y + pr[14]*h3.z + pr[15]*h3.w;
                // softmax over n = 16-lane DPP row; |lg| small -> max-free (R7/R8-proven)
                float p = __expf(lg);
                float z = dpp_sum16(p);
                c = p * __builtin_amdgcn_rcpf(z);
            } else {
                c = 0.0625f;                   // softmax of all-zero logits
            }
            acc[0]  = fmaf(c, h0.x, acc[0]);  acc[1]  = fmaf(c, h0.y, acc[1]);
            acc[2]  = fmaf(c, h0.z, acc[2]);  acc[3]  = fmaf(c, h0.w, acc[3]);
            acc[4]  = fmaf(c, h1.x, acc[4]);  acc[5]  = fmaf(c, h1.y, acc[5]);
            acc[6]  = fmaf(c, h1.z, acc[6]);  acc[7]  = fmaf(c, h1.w, acc[7]);
            acc[8]  = fmaf(c, h2.x, acc[8]);  acc[9]  = fmaf(c, h2.y, acc[9]);
            acc[10] = fmaf(c, h2.z, acc[10]); acc[11] = fmaf(c, h2.w, acc[11]);
            acc[12] = fmaf(c, h3.x, acc[12]); acc[13] = fmaf(c, h3.y, acc[13]);
            acc[14] = fmaf(c, h3.z, acc[14]); acc[15] = fmaf(c, h3.w, acc[15]);
        }
    }

    // ---- epilogue: bf16 partial[ic][b][n][e] (thread owns the full row) ----
    unsigned short* pp = partial + (((size_t)ic * B_SZ + b_glb) << 8) + (n << 4);
    uint4 o0 = {pk2(acc[0], acc[1]),  pk2(acc[2], acc[3]),
                pk2(acc[4], acc[5]),  pk2(acc[6], acc[7])};
    uint4 o1 = {pk2(acc[8], acc[9]),  pk2(acc[10], acc[11]),
                pk2(acc[12], acc[13]), pk2(acc[14], acc[15])};
    *(uint4*)pp = o0;
    *(uint4*)(pp + 8) = o1;
}

// ---- sum 72 bf16 slices (uint = 2 els per thread). !FINAL: acc fp32.
// FINAL: +B, squash (8-lane DPP row = one e-row), write out fp32. ----
template<bool FINAL>
__global__ __launch_bounds__(256)
void caps_reduce(const unsigned int* __restrict__ partial, const float* __restrict__ Bb,
                 float2* __restrict__ acc, float2* __restrict__ out)
{
    const int g2 = blockIdx.x * 256 + threadIdx.x;   // g2 = b*128 + n*8 + ep
    float t0 = 0.f, t1 = 0.f;
    #pragma unroll 8
    for (int s = 0; s < ICN; ++s) {
        unsigned u = partial[(size_t)s * (OUT_ELEMS / 2) + g2];
        t0 += bf2f((unsigned short)(u & 0xFFFF));
        t1 += bf2f((unsigned short)(u >> 16));
    }
    if (!FINAL) {
        acc[g2] = make_float2(t0, t1);
    } else {
        const int n = (g2 >> 3) & 15, ep = g2 & 7;
        float2 bb = *(const float2*)(Bb + n * 16 + 2 * ep);
        t0 += bb.x; t1 += bb.y;
        float s2 = dpp_sum8(t0 * t0 + t1 * t1);
        float sc = sqrtf(s2) / (1.0f + s2);
        out[g2] = make_float2(t0 * sc, t1 * sc);
    }
}

extern "C" void kernel_launch(void* const* d_in, const int* in_sizes, int n_in,
                              void* d_out, int out_size, void* d_ws, size_t ws_size,
                              hipStream_t stream)
{
    const float* x  = (const float*)d_in[0];   // [128,1152,8]
    const float* W  = (const float*)d_in[1];   // [16,1152,16,8]
    const float* Bb = (const float*)d_in[2];   // [16,16]
    float2* out = (float2*)d_out;              // [128,16,16] fp32

    float* accA = (float*)d_ws;                                   // 128 KB
    float* accB = accA + OUT_ELEMS;                               // 128 KB
    unsigned short* WB = (unsigned short*)(accB + OUT_ELEMS);     // 4.72 MB
    unsigned short* XT = WB + (size_t)N_CAPS * IN_CAPS * DIM * 8; // 2.36 MB
    unsigned short* partial = XT + (size_t)B_SZ * IN_CAPS * 8;    // 72 x 64 KB

    conv_xw<<<1152 + 576, 256, 0, stream>>>(W, x, WB, XT);

    dim3 pg(B_SZ / 16, ICN);   // 8 x 72 = 576 blocks (x-major: W-slice L2 reuse)

    caps_pass<0><<<pg, 256, 0, stream>>>(XT, WB, Bb, nullptr, nullptr, partial);
    caps_reduce<false><<<OUT_ELEMS / 512, 256, 0, stream>>>((const unsigned*)partial, Bb, (float2*)accA, nullptr);
    caps_pass<1><<<pg, 256, 0, stream>>>(XT, WB, Bb, accA, nullptr, partial);
    caps_reduce<false><<<OUT_ELEMS / 512, 256, 0, stream>>>((const unsigned*)partial, Bb, (float2*)accB, nullptr);
    caps_pass<2><<<pg, 256, 0, stream>>>(XT, WB, Bb, accA, accB, partial);
    caps_reduce<true><<<OUT_ELEMS / 512, 256, 0, stream>>>((const unsigned*)partial, Bb, nullptr, out);
}

// Round 10
// 139.534 us; speedup vs baseline: 4.2596x; 1.0548x over previous
//
#include <hip/hip_runtime.h>
#include <hip/hip_bf16.h>

#define B_SZ 128
#define IN_CAPS 1152
#define N_CAPS 16
#define DIM 16

#define IPB 8                         // i's per pass-block (1 i per chunk, dbuf)
#define ICN (IN_CAPS / IPB)           // 144 partial slices
#define OUT_ELEMS (B_SZ * N_CAPS * DIM)   // 32768
// LDS hat tile (bf16 pairs, uint units): [slot(2)][b(16)][n(16)][ep(8)]
#define NSTRU 12                      // n-stride: 8 uints + 4 pad (16B-aligned)
#define BSTRU 196                     // b-stride: 16*12 + 4  (16B-aligned, mod32=4)
#define SLOTU (16 * BSTRU)            // 3136 uints = 12.5 KB per slot

typedef __attribute__((ext_vector_type(8))) short bf16x8;   // MFMA A/B frag
typedef __attribute__((ext_vector_type(4))) float f32x4;    // MFMA C/D frag

__device__ __forceinline__ unsigned short f2bf(float f) {   // RNE
    unsigned u = __float_as_uint(f);
    u = u + 0x7fffu + ((u >> 16) & 1u);
    return (unsigned short)(u >> 16);
}
__device__ __forceinline__ unsigned pk2(float lo, float hi) {
    return ((unsigned)f2bf(hi) << 16) | f2bf(lo);
}
__device__ __forceinline__ unsigned cvtpk(float lo, float hi) {   // HW packed cvt (RNE)
    union { __hip_bfloat162 h; unsigned u; } c;
    c.h = __float22bfloat162_rn(make_float2(lo, hi));
    return c.u;
}

// DPP sums (VALU pipe — no DS traffic)
__device__ __forceinline__ float dpp_sum16(float v) {
    v += __int_as_float(__builtin_amdgcn_update_dpp(0, __float_as_int(v), 0xB1, 0xF, 0xF, true));
    v += __int_as_float(__builtin_amdgcn_update_dpp(0, __float_as_int(v), 0x4E, 0xF, 0xF, true));
    v += __int_as_float(__builtin_amdgcn_update_dpp(0, __float_as_int(v), 0x124, 0xF, 0xF, true));
    v += __int_as_float(__builtin_amdgcn_update_dpp(0, __float_as_int(v), 0x128, 0xF, 0xF, true));
    return v;
}
__device__ __forceinline__ float dpp_sum8(float v) {
    v += __int_as_float(__builtin_amdgcn_update_dpp(0, __float_as_int(v), 0xB1, 0xF, 0xF, true));
    v += __int_as_float(__builtin_amdgcn_update_dpp(0, __float_as_int(v), 0x4E, 0xF, 0xF, true));
    v += __int_as_float(__builtin_amdgcn_update_dpp(0, __float_as_int(v), 0x141, 0xF, 0xF, true));
    return v;
}

// ---- prep (fused): blocks [0,1152): W -> WB bf16; [1152,1728): x -> XT[i][b][d] bf16 ----
__global__ __launch_bounds__(256)
void conv_xw(const float* __restrict__ W, const float* __restrict__ x,
             unsigned short* __restrict__ WB, unsigned short* __restrict__ XT)
{
    const int tid = threadIdx.x;
    if (blockIdx.x < 1152) {
        size_t g = (size_t)blockIdx.x * 256 + tid;
        const float4* src = (const float4*)(W + g * 8);
        float4 a = src[0], b = src[1];
        uint4 o = {pk2(a.x, a.y), pk2(a.z, a.w), pk2(b.x, b.y), pk2(b.z, b.w)};
        *(uint4*)(WB + g * 8) = o;
    } else {
        const int bx = blockIdx.x - 1152;
        const int i = bx * 2 + (tid >> 7);
        const int b = tid & 127;
        const float4* src = (const float4*)(x + ((size_t)b * IN_CAPS + i) * 8);
        float4 a = src[0], c = src[1];
        uint4 o = {pk2(a.x, a.y), pk2(a.z, a.w), pk2(c.x, c.y), pk2(c.z, c.w)};
        *(uint4*)(XT + ((size_t)i * B_SZ + b) * 8) = o;
    }
}

// Produce one i of hat into a slot. Swapped MFMA roles: A = W (m = e), B = x
// (col = b, k>=8 rows zeroed). D: col(lane&15) = b, rows(reg) = e = 4q+r ->
// 4 consecutive e's IN REGISTER -> pack bf16 pairs -> one ds_write_b64.
__device__ __forceinline__ void produce_i(
    const unsigned short* __restrict__ XT, const unsigned short* __restrict__ WB,
    unsigned* __restrict__ slot, int i, int bt, int w, int q, int em)
{
    uint4 xu = {0u, 0u, 0u, 0u};
    if (q == 0)   // B[k>=8][*] = 0 kills A's k>=8 garbage
        xu = *(const uint4*)(XT + ((size_t)i * B_SZ + bt * 16 + em) * 8);
    union { uint4 u; bf16x8 v; } bx; bx.u = xu;
    #pragma unroll
    for (int np = 0; np < 4; ++np) {
        const int nn = 4 * w + np;
        bf16x8 av = *(const bf16x8*)(WB + (((size_t)nn * IN_CAPS + i) * DIM + em) * 8);
        f32x4 cz = {0.f, 0.f, 0.f, 0.f};
        f32x4 d = __builtin_amdgcn_mfma_f32_16x16x32_bf16(av, bx.v, cz, 0, 0, 0);
        // lane (q, em=b) holds hat[b=em][e=4q..4q+3] for capsule nn
        uint2 o = {cvtpk(d[0], d[1]), cvtpk(d[2], d[3])};
        *(uint2*)(slot + (size_t)em * BSTRU + nn * NSTRU + 2 * q) = o;
    }
}

// ---- fused routing pass ----
// R9 lesson: 41.5KB LDS -> 2.25 blocks/CU + produce|barrier|consume|barrier
// exposed full WB-load latency every chunk (pass ~38us vs ~10us model). Now:
// hat bf16-packed (25KB, 2 slots) + true dbuf (produce ch+1 || consume ch,
// ONE barrier/chunk) so producer loads overlap consumer VALU.
// Consumer thread: n = lane&15, b_loc = 4*wave + (lane>>4); e fully in-thread.
// MODE 0: c=1/16.  MODE 1: pr = squash(accA+B).  MODE 2: pr = sq(accA+B)+sq(accB+B).
template<int MODE>
__global__ __launch_bounds__(256)
void caps_pass(const unsigned short* __restrict__ XT, const unsigned short* __restrict__ WB,
               const float* __restrict__ Bb,
               const float* __restrict__ accA, const float* __restrict__ accB,
               unsigned short* __restrict__ partial)
{
    const int tid  = threadIdx.x;
    const int lane = tid & 63;
    const int w    = tid >> 6;
    const int em   = lane & 15;       // producer: m(A)=e col? no: A m=e is lane&15; also B col=b. consumer: n
    const int q    = lane >> 4;
    const int bt   = blockIdx.x;      // 0..7
    const int ic   = blockIdx.y;      // 0..143
    const int i0   = ic * IPB;
    const int n    = em;
    const int b_loc = 4 * w + q;
    const int b_glb = bt * 16 + b_loc;

    __shared__ unsigned hatp[2 * SLOTU];   // 25.1 KB -> 6 blocks/CU (LDS)

    // ---- prologue: pr[e] for this thread's (b_glb, n) ----
    float pr[16];
    if (MODE > 0) {
        const float4* bbp = (const float4*)(Bb + (n << 4));
        const float4* ap  = (const float4*)(accA + ((size_t)b_glb << 8) + (n << 4));
        float s[16], s2 = 0.f;
        #pragma unroll
        for (int k4 = 0; k4 < 4; ++k4) {
            float4 a = ap[k4], bb = bbp[k4];
            s[4*k4+0] = a.x + bb.x; s[4*k4+1] = a.y + bb.y;
            s[4*k4+2] = a.z + bb.z; s[4*k4+3] = a.w + bb.w;
        }
        #pragma unroll
        for (int e = 0; e < 16; ++e) s2 = fmaf(s[e], s[e], s2);
        float sc = sqrtf(s2) / (1.0f + s2);
        #pragma unroll
        for (int e = 0; e < 16; ++e) pr[e] = s[e] * sc;
        if (MODE == 2) {
            const float4* ap2 = (const float4*)(accB + ((size_t)b_glb << 8) + (n << 4));
            float t[16], t2 = 0.f;
            #pragma unroll
            for (int k4 = 0; k4 < 4; ++k4) {
                float4 a = ap2[k4], bb = bbp[k4];
                t[4*k4+0] = a.x + bb.x; t[4*k4+1] = a.y + bb.y;
                t[4*k4+2] = a.z + bb.z; t[4*k4+3] = a.w + bb.w;
            }
            #pragma unroll
            for (int e = 0; e < 16; ++e) t2 = fmaf(t[e], t[e], t2);
            float sc2 = sqrtf(t2) / (1.0f + t2);
            #pragma unroll
            for (int e = 0; e < 16; ++e) pr[e] = fmaf(t[e], sc2, pr[e]);
        }
        #pragma unroll
        for (int e = 0; e < 16; ++e)
            asm volatile("" : "+v"(pr[e]));   // pin: no remat across the chunk loop
    }

    float acc[16];
    #pragma unroll
    for (int e = 0; e < 16; ++e) acc[e] = 0.f;

    produce_i(XT, WB, hatp, i0, bt, w, q, em);   // chunk 0 -> slot 0

    #pragma unroll 1
    for (int ch = 0; ch < IPB; ++ch) {
        __syncthreads();
        if (ch + 1 < IPB)   // overlap: next chunk's loads+MFMA run against this consume
            produce_i(XT, WB, hatp + ((ch + 1) & 1) * SLOTU, i0 + ch + 1, bt, w, q, em);

        // ---- consume chunk ch (slot ch&1): e fully in-thread ----
        const unsigned* rowp = hatp + (ch & 1) * SLOTU + (size_t)b_loc * BSTRU + n * NSTRU;
        uint4 u0 = *(const uint4*)rowp;          // e 0..7 (bf16 pairs)
        uint4 u1 = *(const uint4*)(rowp + 4);    // e 8..15
        float h[16];
        {
            unsigned uu[8] = {u0.x, u0.y, u0.z, u0.w, u1.x, u1.y, u1.z, u1.w};
            #pragma unroll
            for (int j = 0; j < 8; ++j) {
                h[2*j]   = __uint_as_float(uu[j] << 16);
                h[2*j+1] = __uint_as_float(uu[j] & 0xFFFF0000u);
            }
        }
        float c;
        if (MODE > 0) {
            float lg = 0.f;
            #pragma unroll
            for (int e = 0; e < 16; ++e) lg = fmaf(pr[e], h[e], lg);
            float p = __expf(lg);                 // |lg| small -> max-free (R7-R9 proven)
            float z = dpp_sum16(p);               // softmax over n = 16-lane DPP row
            c = p * __builtin_amdgcn_rcpf(z);
        } else {
            c = 0.0625f;                          // softmax of all-zero logits
        }
        #pragma unroll
        for (int e = 0; e < 16; ++e) acc[e] = fmaf(c, h[e], acc[e]);
    }

    // ---- epilogue: bf16 partial[ic][b][n][e] (thread owns the row) ----
    unsigned short* pp = partial + (((size_t)ic * B_SZ + b_glb) << 8) + (n << 4);
    uint4 o0 = {pk2(acc[0], acc[1]),   pk2(acc[2], acc[3]),
                pk2(acc[4], acc[5]),   pk2(acc[6], acc[7])};
    uint4 o1 = {pk2(acc[8], acc[9]),   pk2(acc[10], acc[11]),
                pk2(acc[12], acc[13]), pk2(acc[14], acc[15])};
    *(uint4*)pp = o0;
    *(uint4*)(pp + 8) = o1;
}

// ---- reduce 144 bf16 slices. Grouped: 256 blocks x 256 thr; thread (grp=tid>>6)
// sums 36 slices at uint pos (2 els); LDS combine; FINAL adds B + squash (8-lane DPP). ----
template<bool FINAL>
__global__ __launch_bounds__(256)
void caps_reduce(const unsigned* __restrict__ partial, const float* __restrict__ Bb,
                 float2* __restrict__ acc, float2* __restrict__ out)
{
    const int tid = threadIdx.x;
    const int ps  = tid & 63;
    const int grp = tid >> 6;
    const int pos = blockIdx.x * 64 + ps;        // uint index in [0, 16384)

    float t0 = 0.f, t1 = 0.f;
    #pragma unroll 6
    for (int k = 0; k < ICN / 4; ++k) {
        unsigned u = partial[(size_t)(grp * (ICN / 4) + k) * (OUT_ELEMS / 2) + pos];
        t0 += __uint_as_float(u << 16);
        t1 += __uint_as_float(u & 0xFFFF0000u);
    }
    __shared__ float2 red[4][64];
    red[grp][ps] = make_float2(t0, t1);
    __syncthreads();

    if (tid < 64) {
        float2 a = red[0][ps], b = red[1][ps], c = red[2][ps], d = red[3][ps];
        float v0 = a.x + b.x + c.x + d.x;
        float v1 = a.y + b.y + c.y + d.y;
        if (!FINAL) {
            acc[pos] = make_float2(v0, v1);
        } else {
            const int n = (pos >> 3) & 15, ep = pos & 7;
            float2 bb = *(const float2*)(Bb + n * 16 + 2 * ep);
            v0 += bb.x; v1 += bb.y;
            float s2 = dpp_sum8(v0 * v0 + v1 * v1);   // e-row = 8 consecutive lanes
            float sc = sqrtf(s2) / (1.0f + s2);
            out[pos] = make_float2(v0 * sc, v1 * sc);
        }
    }
}

extern "C" void kernel_launch(void* const* d_in, const int* in_sizes, int n_in,
                              void* d_out, int out_size, void* d_ws, size_t ws_size,
                              hipStream_t stream)
{
    const float* x  = (const float*)d_in[0];   // [128,1152,8]
    const float* W  = (const float*)d_in[1];   // [16,1152,16,8]
    const float* Bb = (const float*)d_in[2];   // [16,16]
    float2* out = (float2*)d_out;              // [128,16,16] fp32

    float* accA = (float*)d_ws;                                   // 128 KB
    float* accB = accA + OUT_ELEMS;                               // 128 KB
    unsigned short* WB = (unsigned short*)(accB + OUT_ELEMS);     // 4.72 MB
    unsigned short* XT = WB + (size_t)N_CAPS * IN_CAPS * DIM * 8; // 2.36 MB
    unsigned short* partial = XT + (size_t)B_SZ * IN_CAPS * 8;    // 144 x 64 KB = 9.4 MB

    conv_xw<<<1728, 256, 0, stream>>>(W, x, WB, XT);

    dim3 pg(B_SZ / 16, ICN);   // 8 x 144 = 1152 blocks

    caps_pass<0><<<pg, 256, 0, stream>>>(XT, WB, Bb, nullptr, nullptr, partial);
    caps_reduce<false><<<256, 256, 0, stream>>>((const unsigned*)partial, Bb, (float2*)accA, nullptr);
    caps_pass<1><<<pg, 256, 0, stream>>>(XT, WB, Bb, accA, nullptr, partial);
    caps_reduce<false><<<256, 256, 0, stream>>>((const unsigned*)partial, Bb, (float2*)accB, nullptr);
    caps_pass<2><<<pg, 256, 0, stream>>>(XT, WB, Bb, accA, accB, partial);
    caps_reduce<true><<<256, 256, 0, stream>>>((const unsigned*)partial, Bb, nullptr, out);
}